// Round 1
// 546.042 us; speedup vs baseline: 1.1227x; 1.1227x over previous
//
#include <hip/hip_runtime.h>
#include <hip/hip_bf16.h>

#define E_ 8
#define H_ 2048
#define I_ 1024
#define T_ 16384
#define BK 64
#define BM 256
#define MT_ (T_ / BM + E_)   // 72 max m-tiles (64 full + up to 8 partial)
#define SLOT 32768           // ushorts per LDS slot (64 KB); 2 slots = 128 KB

typedef __bf16 bf16x8 __attribute__((ext_vector_type(8)));
typedef float f32x4 __attribute__((ext_vector_type(4)));

__device__ __forceinline__ unsigned short f2bf(float f) {
  unsigned int x = __float_as_uint(f);
  x += 0x7FFFu + ((x >> 16) & 1u);   // round-to-nearest-even
  return (unsigned short)(x >> 16);
}

__device__ __forceinline__ void gl_lds16(const void* g, void* s) {
  __builtin_amdgcn_global_load_lds(
      (const __attribute__((address_space(1))) void*)g,
      (__attribute__((address_space(3))) void*)s, 16, 0, 0);
}

// Counted wait: never drain to 0 in the main loop (T4). "memory" clobber keeps
// all memory ops (gl_lds DMAs, LDS reads) ordered against it.
#define VMCNT4 asm volatile("s_waitcnt vmcnt(4)" ::: "memory")
// Raw barrier (NO implicit vmcnt(0) drain, unlike __syncthreads) + scheduling
// fence so the compiler cannot hoist the following ds_reads above it.
#define BARRIER                      \
  do {                               \
    __builtin_amdgcn_s_barrier();    \
    __builtin_amdgcn_sched_barrier(0); \
  } while (0)

// 16-MFMA phase cluster wrapped in setprio (T5: pays off in phase-split schedules)
#define MFMA16(ACC, AF, BF)                                                     \
  do {                                                                          \
    __builtin_amdgcn_s_setprio(1);                                              \
    _Pragma("unroll") for (int ks = 0; ks < 2; ks++)                            \
    _Pragma("unroll") for (int mi = 0; mi < 4; mi++)                            \
    _Pragma("unroll") for (int ni = 0; ni < 2; ni++)                            \
      ACC[mi][ni] = __builtin_amdgcn_mfma_f32_16x16x32_bf16(                    \
          AF[mi][ks], BF[ni][ks], ACC[mi][ni], 0, 0, 0);                        \
    __builtin_amdgcn_s_setprio(0);                                              \
  } while (0)

// Map linear m-tile index -> (expert, row0, rowEnd). Returns false for idle blocks.
__device__ __forceinline__ bool find_tile(const int* gs, int tile, int& e,
                                          int& row0, int& rowEnd) {
  int base = 0, tb = 0;
  e = -1;
  for (int i = 0; i < E_; i++) {
    int g = gs[i];
    int nt = (g + BM - 1) >> 8;
    if (e < 0 && tile < tb + nt) {
      e = i;
      row0 = base + (tile - tb) * BM;
      rowEnd = base + g;
    }
    tb += nt;
    base += g;
  }
  return e >= 0;
}

// ---------------- conversion kernels (unchanged) ----------------

__global__ void cvt_hs(const float* __restrict__ in, ushort* __restrict__ out) {
  size_t i = ((size_t)blockIdx.x * 256 + threadIdx.x) * 8;
  float4 a = *(const float4*)(in + i);
  float4 b = *(const float4*)(in + i + 4);
  union { ushort u[8]; uint4 v; } p;
  p.u[0] = f2bf(a.x); p.u[1] = f2bf(a.y); p.u[2] = f2bf(a.z); p.u[3] = f2bf(a.w);
  p.u[4] = f2bf(b.x); p.u[5] = f2bf(b.y); p.u[6] = f2bf(b.z); p.u[7] = f2bf(b.w);
  *(uint4*)(out + i) = p.v;
}

__global__ void cvt_tr(const float* __restrict__ in, ushort* __restrict__ out,
                       int K, int N) {
  __shared__ ushort tile[64][65];
  int n0 = blockIdx.x * 64, k0 = blockIdx.y * 64;
  const float* src = in + (size_t)blockIdx.z * K * N;
  ushort* dst = out + (size_t)blockIdx.z * K * N;
  int t = threadIdx.x;
  int rb = t >> 4, c4 = (t & 15) * 4;
#pragma unroll
  for (int i = 0; i < 4; i++) {
    int r = rb + i * 16;
    float4 v = *(const float4*)(src + (size_t)(k0 + r) * N + n0 + c4);
    tile[r][c4 + 0] = f2bf(v.x);
    tile[r][c4 + 1] = f2bf(v.y);
    tile[r][c4 + 2] = f2bf(v.z);
    tile[r][c4 + 3] = f2bf(v.w);
  }
  __syncthreads();
#pragma unroll
  for (int i = 0; i < 2; i++) {
    int c = t + i * 256;
    int n = c >> 3, kc = c & 7;
    union { ushort u[8]; uint4 v; } p;
#pragma unroll
    for (int j = 0; j < 8; j++) p.u[j] = tile[kc * 8 + j][n];
    *(uint4*)(dst + (size_t)(n0 + n) * K + k0 + kc * 8) = p.v;
  }
}

// ---------------- fused gate/up GEMM + SwiGLU: 256x128 tile, 8 waves ----------------
// LDS slot (64 KB, x2 dbuf): A [256x64] @0, G [128x64] @16384, U [128x64] @24576.
// Per-unit chunk layout: chunk c -> (r = c>>3, kc = (c&7)^(r&7)) XOR swizzle, LDS
// written linearly by global_load_lds (pre-swizzled global source).
// K-tile = 4 phases; phase p stages unit p of tile t+1 (order A-lo, G, U, A-hi) and
// computes one quadrant: G*mh0, U*mh0, G*mh1, U*mh1. Uniform vmcnt(4) at phases
// 0-2 retires exactly the unit that phase reads; queue never drains to 0.
__global__ __launch_bounds__(512, 2) void gemm_gateup(
    const ushort* __restrict__ A, const ushort* __restrict__ BgT,
    const ushort* __restrict__ BuT, const int* __restrict__ gs,
    ushort* __restrict__ Hb) {
  extern __shared__ __align__(16) ushort ls[];

  int e, row0, rowEnd;
  if (!find_tile(gs, blockIdx.x, e, row0, rowEnd)) return;
  const int n0 = blockIdx.y * 128;

  const int t = threadIdx.x;
  const int lane = t & 63;
  const int w = t >> 6;          // 0..7
  const int wm = w & 1, wn = w >> 1;  // 2M x 4N wave grid
  const int ldW = w * 512;       // wave's 64-chunk dst slice within a unit

  // staging source offsets (pre-swizzled), 2 loads per thread per unit
  int oAlo[2], oAhi[2], oB[2];
#pragma unroll
  for (int l = 0; l < 2; l++) {
    int c = l * 512 + t;
    int r = c >> 3, kc = (c & 7) ^ (r & 7);
    int a0 = row0 + r;       if (a0 > T_ - 1) a0 = T_ - 1;
    int a1 = row0 + 128 + r; if (a1 > T_ - 1) a1 = T_ - 1;
    oAlo[l] = a0 * H_ + kc * 8;
    oAhi[l] = a1 * H_ + kc * 8;
    oB[l] = (e * I_ + n0 + r) * H_ + kc * 8;
  }

  // fragment read addressing (swizzled)
  const int l15 = lane & 15, l7 = lane & 7, lk = lane >> 4;
  const int s0 = (lk ^ l7) * 8, s1 = ((lk + 4) ^ l7) * 8;
  const int arow = (wm * 64 + l15) * 64;   // + mh*8192 + mi*1024
  const int brow = (wn * 32 + l15) * 64;   // + ni*1024

  f32x4 accG0[4][2], accG1[4][2], accU0[4][2], accU1[4][2];
#pragma unroll
  for (int mi = 0; mi < 4; mi++)
#pragma unroll
    for (int ni = 0; ni < 2; ni++) {
      accG0[mi][ni] = (f32x4){0.f, 0.f, 0.f, 0.f};
      accG1[mi][ni] = (f32x4){0.f, 0.f, 0.f, 0.f};
      accU0[mi][ni] = (f32x4){0.f, 0.f, 0.f, 0.f};
      accU1[mi][ni] = (f32x4){0.f, 0.f, 0.f, 0.f};
    }

  // prologue: stage all 4 units of tile 0 into slot 0 (same order as steady state)
  gl_lds16(A + oAlo[0], ls + 0 + ldW);
  gl_lds16(A + oAlo[1], ls + 4096 + ldW);
  gl_lds16(BgT + oB[0], ls + 16384 + ldW);
  gl_lds16(BgT + oB[1], ls + 16384 + 4096 + ldW);
  gl_lds16(BuT + oB[0], ls + 24576 + ldW);
  gl_lds16(BuT + oB[1], ls + 24576 + 4096 + ldW);
  gl_lds16(A + oAhi[0], ls + 8192 + ldW);
  gl_lds16(A + oAhi[1], ls + 8192 + 4096 + ldW);

#pragma unroll 2
  for (int tt = 0; tt < H_ / BK; tt++) {
    const int p = tt & 1, q = p ^ 1;
    const ushort* sa = ls + p * SLOT;
    ushort* sq = ls + q * SLOT;
    const int kn = (tt + 1 < H_ / BK ? tt + 1 : tt) * BK;  // clamped re-stage on last tile
    bf16x8 af[4][2], gf[2][2], uf[2][2];

    // ---- phase 0: retire {A-lo,G}(t); stage A-lo(t+1); MFMA G x mh0 ----
    VMCNT4; BARRIER;
    gl_lds16(A + oAlo[0] + kn, sq + 0 + ldW);
    gl_lds16(A + oAlo[1] + kn, sq + 4096 + ldW);
#pragma unroll
    for (int mi = 0; mi < 4; mi++) {
      af[mi][0] = *(const bf16x8*)(sa + arow + mi * 1024 + s0);
      af[mi][1] = *(const bf16x8*)(sa + arow + mi * 1024 + s1);
    }
#pragma unroll
    for (int ni = 0; ni < 2; ni++) {
      gf[ni][0] = *(const bf16x8*)(sa + 16384 + brow + ni * 1024 + s0);
      gf[ni][1] = *(const bf16x8*)(sa + 16384 + brow + ni * 1024 + s1);
    }
    MFMA16(accG0, af, gf);

    // ---- phase 1: retire U(t); stage G(t+1); MFMA U x mh0 (A frags reused) ----
    VMCNT4; BARRIER;
    gl_lds16(BgT + oB[0] + kn, sq + 16384 + ldW);
    gl_lds16(BgT + oB[1] + kn, sq + 16384 + 4096 + ldW);
#pragma unroll
    for (int ni = 0; ni < 2; ni++) {
      uf[ni][0] = *(const bf16x8*)(sa + 24576 + brow + ni * 1024 + s0);
      uf[ni][1] = *(const bf16x8*)(sa + 24576 + brow + ni * 1024 + s1);
    }
    MFMA16(accU0, af, uf);

    // ---- phase 2: retire A-hi(t); stage U(t+1); MFMA G x mh1 (G frags reused) ----
    VMCNT4; BARRIER;
    gl_lds16(BuT + oB[0] + kn, sq + 24576 + ldW);
    gl_lds16(BuT + oB[1] + kn, sq + 24576 + 4096 + ldW);
#pragma unroll
    for (int mi = 0; mi < 4; mi++) {
      af[mi][0] = *(const bf16x8*)(sa + 8192 + arow + mi * 1024 + s0);
      af[mi][1] = *(const bf16x8*)(sa + 8192 + arow + mi * 1024 + s1);
    }
    MFMA16(accG1, af, gf);

    // ---- phase 3: stage A-hi(t+1); MFMA U x mh1 (A,U frags reused) ----
    BARRIER;
    gl_lds16(A + oAhi[0] + kn, sq + 8192 + ldW);
    gl_lds16(A + oAhi[1] + kn, sq + 8192 + 4096 + ldW);
    MFMA16(accU1, af, uf);
  }

  // epilogue: h = silu(g)*u, bf16 store. C/D: col=lane&15, row=(lane>>4)*4+r
  const int cr = row0 + wm * 64 + (lk << 2);
  const int cc = n0 + wn * 32 + l15;
#pragma unroll
  for (int mh = 0; mh < 2; mh++)
#pragma unroll
    for (int mi = 0; mi < 4; mi++)
#pragma unroll
      for (int ni = 0; ni < 2; ni++)
#pragma unroll
        for (int r = 0; r < 4; r++) {
          int row = cr + mh * 128 + mi * 16 + r;
          if (row < rowEnd) {
            float g = mh ? accG1[mi][ni][r] : accG0[mi][ni][r];
            float u = mh ? accU1[mi][ni][r] : accU0[mi][ni][r];
            float h = (g / (1.0f + __expf(-g))) * u;
            Hb[(size_t)row * I_ + cc + ni * 16] = f2bf(h);
          }
        }
}

// ---------------- down GEMM: 256x256 tile, 8 waves ----------------
// LDS slot: A [256x64] @0 (lo/hi), B [256x64] @16384 (lo/hi). Wave owns 128x64
// output split across both halves of M and N (mh,nh in {0,1}) so the uniform
// vmcnt(4) schedule works: stage order A-lo, B-lo, B-hi, A-hi; phases
// (mh,nh) = (0,0),(0,1),(1,1),(1,0).
__global__ __launch_bounds__(512, 2) void gemm_down(
    const ushort* __restrict__ A, const ushort* __restrict__ BdT,
    const int* __restrict__ gs, float* __restrict__ Out) {
  extern __shared__ __align__(16) ushort ls[];

  int e, row0, rowEnd;
  if (!find_tile(gs, blockIdx.x, e, row0, rowEnd)) return;
  const int n0 = blockIdx.y * 256;

  const int t = threadIdx.x;
  const int lane = t & 63;
  const int w = t >> 6;
  const int wm = w & 1, wn = w >> 1;
  const int ldW = w * 512;

  int oAlo[2], oAhi[2], oBlo[2], oBhi[2];
#pragma unroll
  for (int l = 0; l < 2; l++) {
    int c = l * 512 + t;
    int r = c >> 3, kc = (c & 7) ^ (r & 7);
    int a0 = row0 + r;       if (a0 > T_ - 1) a0 = T_ - 1;
    int a1 = row0 + 128 + r; if (a1 > T_ - 1) a1 = T_ - 1;
    oAlo[l] = a0 * I_ + kc * 8;
    oAhi[l] = a1 * I_ + kc * 8;
    oBlo[l] = (e * H_ + n0 + r) * I_ + kc * 8;
    oBhi[l] = (e * H_ + n0 + 128 + r) * I_ + kc * 8;
  }

  const int l15 = lane & 15, l7 = lane & 7, lk = lane >> 4;
  const int s0 = (lk ^ l7) * 8, s1 = ((lk + 4) ^ l7) * 8;
  const int arow = (wm * 64 + l15) * 64;
  const int brow = (wn * 32 + l15) * 64;

  f32x4 acc00[4][2], acc01[4][2], acc11[4][2], acc10[4][2];  // [mh][nh]
#pragma unroll
  for (int mi = 0; mi < 4; mi++)
#pragma unroll
    for (int ni = 0; ni < 2; ni++) {
      acc00[mi][ni] = (f32x4){0.f, 0.f, 0.f, 0.f};
      acc01[mi][ni] = (f32x4){0.f, 0.f, 0.f, 0.f};
      acc11[mi][ni] = (f32x4){0.f, 0.f, 0.f, 0.f};
      acc10[mi][ni] = (f32x4){0.f, 0.f, 0.f, 0.f};
    }

  // prologue: tile 0 -> slot 0, order A-lo, B-lo, B-hi, A-hi
  gl_lds16(A + oAlo[0], ls + 0 + ldW);
  gl_lds16(A + oAlo[1], ls + 4096 + ldW);
  gl_lds16(BdT + oBlo[0], ls + 16384 + ldW);
  gl_lds16(BdT + oBlo[1], ls + 16384 + 4096 + ldW);
  gl_lds16(BdT + oBhi[0], ls + 24576 + ldW);
  gl_lds16(BdT + oBhi[1], ls + 24576 + 4096 + ldW);
  gl_lds16(A + oAhi[0], ls + 8192 + ldW);
  gl_lds16(A + oAhi[1], ls + 8192 + 4096 + ldW);

#pragma unroll 2
  for (int tt = 0; tt < I_ / BK; tt++) {
    const int p = tt & 1, q = p ^ 1;
    const ushort* sa = ls + p * SLOT;
    ushort* sq = ls + q * SLOT;
    const int kn = (tt + 1 < I_ / BK ? tt + 1 : tt) * BK;
    bf16x8 af[4][2], bf0[2][2], bf1[2][2];

    // ---- phase 0: retire {A-lo,B-lo}(t); stage A-lo(t+1); MFMA (mh0,nh0) ----
    VMCNT4; BARRIER;
    gl_lds16(A + oAlo[0] + kn, sq + 0 + ldW);
    gl_lds16(A + oAlo[1] + kn, sq + 4096 + ldW);
#pragma unroll
    for (int mi = 0; mi < 4; mi++) {
      af[mi][0] = *(const bf16x8*)(sa + arow + mi * 1024 + s0);
      af[mi][1] = *(const bf16x8*)(sa + arow + mi * 1024 + s1);
    }
#pragma unroll
    for (int ni = 0; ni < 2; ni++) {
      bf0[ni][0] = *(const bf16x8*)(sa + 16384 + brow + ni * 1024 + s0);
      bf0[ni][1] = *(const bf16x8*)(sa + 16384 + brow + ni * 1024 + s1);
    }
    MFMA16(acc00, af, bf0);

    // ---- phase 1: retire B-hi(t); stage B-lo(t+1); MFMA (mh0,nh1) ----
    VMCNT4; BARRIER;
    gl_lds16(BdT + oBlo[0] + kn, sq + 16384 + ldW);
    gl_lds16(BdT + oBlo[1] + kn, sq + 16384 + 4096 + ldW);
#pragma unroll
    for (int ni = 0; ni < 2; ni++) {
      bf1[ni][0] = *(const bf16x8*)(sa + 16384 + 8192 + brow + ni * 1024 + s0);
      bf1[ni][1] = *(const bf16x8*)(sa + 16384 + 8192 + brow + ni * 1024 + s1);
    }
    MFMA16(acc01, af, bf1);

    // ---- phase 2: retire A-hi(t); stage B-hi(t+1); MFMA (mh1,nh1) ----
    VMCNT4; BARRIER;
    gl_lds16(BdT + oBhi[0] + kn, sq + 24576 + ldW);
    gl_lds16(BdT + oBhi[1] + kn, sq + 24576 + 4096 + ldW);
#pragma unroll
    for (int mi = 0; mi < 4; mi++) {
      af[mi][0] = *(const bf16x8*)(sa + 8192 + arow + mi * 1024 + s0);
      af[mi][1] = *(const bf16x8*)(sa + 8192 + arow + mi * 1024 + s1);
    }
    MFMA16(acc11, af, bf1);

    // ---- phase 3: stage A-hi(t+1); MFMA (mh1,nh0) ----
    BARRIER;
    gl_lds16(A + oAhi[0] + kn, sq + 8192 + ldW);
    gl_lds16(A + oAhi[1] + kn, sq + 8192 + 4096 + ldW);
    MFMA16(acc10, af, bf0);
  }

  const int cr = row0 + wm * 64 + (lk << 2);
  const int cc = n0 + wn * 32 + l15;
#pragma unroll
  for (int mh = 0; mh < 2; mh++)
#pragma unroll
    for (int mi = 0; mi < 4; mi++)
#pragma unroll
      for (int nh = 0; nh < 2; nh++)
#pragma unroll
        for (int ni = 0; ni < 2; ni++)
#pragma unroll
          for (int r = 0; r < 4; r++) {
            int row = cr + mh * 128 + mi * 16 + r;
            if (row < rowEnd) {
              float v = mh ? (nh ? acc11[mi][ni][r] : acc10[mi][ni][r])
                           : (nh ? acc01[mi][ni][r] : acc00[mi][ni][r]);
              Out[(size_t)row * H_ + cc + nh * 128 + ni * 16] = v;
            }
          }
}

extern "C" void kernel_launch(void* const* d_in, const int* in_sizes, int n_in,
                              void* d_out, int out_size, void* d_ws, size_t ws_size,
                              hipStream_t stream) {
  const float* hs = (const float*)d_in[0];
  const float* gw = (const float*)d_in[1];
  const float* uw = (const float*)d_in[2];
  const float* dw = (const float*)d_in[3];
  const int* gs = (const int*)d_in[4];
  float* out = (float*)d_out;

  ushort* hsb = (ushort*)d_ws;                       // [T,H]
  ushort* wgT = hsb + (size_t)T_ * H_;               // [E,I,H]
  ushort* wuT = wgT + (size_t)E_ * H_ * I_;          // [E,I,H]
  ushort* wdT = wuT + (size_t)E_ * H_ * I_;          // [E,H,I]
  ushort* hb  = wdT + (size_t)E_ * H_ * I_;          // [T,I]

  (void)hipFuncSetAttribute(reinterpret_cast<const void*>(gemm_gateup),
                            hipFuncAttributeMaxDynamicSharedMemorySize, 131072);
  (void)hipFuncSetAttribute(reinterpret_cast<const void*>(gemm_down),
                            hipFuncAttributeMaxDynamicSharedMemorySize, 131072);

  cvt_hs<<<((size_t)T_ * H_) / (256 * 8), 256, 0, stream>>>(hs, hsb);
  cvt_tr<<<dim3(I_ / 64, H_ / 64, E_), 256, 0, stream>>>(gw, wgT, H_, I_);
  cvt_tr<<<dim3(I_ / 64, H_ / 64, E_), 256, 0, stream>>>(uw, wuT, H_, I_);
  cvt_tr<<<dim3(H_ / 64, I_ / 64, E_), 256, 0, stream>>>(dw, wdT, I_, H_);

  gemm_gateup<<<dim3(MT_, I_ / 128), 512, 131072, stream>>>(hsb, wgT, wuT, gs, hb);
  gemm_down<<<dim3(MT_, H_ / 256), 512, 131072, stream>>>(hb, wdT, gs, out);
}